// Round 1
// baseline (600.165 us; speedup 1.0000x reference)
//
#include <hip/hip_runtime.h>
#include <stdint.h>

typedef __bf16 bf16x8 __attribute__((ext_vector_type(8)));
typedef float  f32x4  __attribute__((ext_vector_type(4)));
typedef short  s16x8  __attribute__((ext_vector_type(8)));

__device__ inline unsigned short f2b(float f) {
  unsigned int u = __builtin_bit_cast(unsigned int, f);
  u += 0x7FFFu + ((u >> 16) & 1u);
  return (unsigned short)(u >> 16);
}
__device__ inline float b2f(unsigned short h) {
  unsigned int u = ((unsigned int)h) << 16;
  return __builtin_bit_cast(float, u);
}

// ---------------- elementwise f32 -> bf16 ----------------
__global__ void k_cvt_bf16(const float* __restrict__ in, unsigned short* __restrict__ out, int n4) {
  int i = blockIdx.x * blockDim.x + threadIdx.x;
  if (i < n4) {
    float4 v = ((const float4*)in)[i];
    ushort4 o;
    o.x = f2b(v.x); o.y = f2b(v.y); o.z = f2b(v.z); o.w = f2b(v.w);
    ((ushort4*)out)[i] = o;
  }
}

// ---------------- transpose f32 [K][N]-segments -> bf16 [N][K] ----------------
// Segments: cols [0,nA) from A (ld=nA), [nA,nA+nB) from Bsrc (ld=nB), rest from Csrc (ld=nB).
__global__ void k_transpose(const float* __restrict__ A, int nA,
                            const float* __restrict__ Bsrc, int nB,
                            const float* __restrict__ Csrc,
                            unsigned short* __restrict__ dst, int K) {
  __shared__ float tile[32][33];
  int n0 = blockIdx.x * 32;
  int k0 = blockIdx.y * 32;
  const float* src; int ldn, noff;
  if (n0 < nA)            { src = A;    ldn = nA; noff = n0; }
  else if (n0 < nA + nB)  { src = Bsrc; ldn = nB; noff = n0 - nA; }
  else                    { src = Csrc; ldn = nB; noff = n0 - nA - nB; }
  int tx = threadIdx.x & 31, ty = threadIdx.x >> 5;
  for (int yy = ty; yy < 32; yy += 8)
    tile[yy][tx] = src[(size_t)(k0 + yy) * ldn + noff + tx];
  __syncthreads();
  for (int yy = ty; yy < 32; yy += 8)
    dst[(size_t)(n0 + yy) * K + k0 + tx] = f2b(tile[tx][yy]);
}

// ---------------- bias concat [2304] ----------------
__global__ void k_bias_concat(const float* __restrict__ bq, const float* __restrict__ bk,
                              const float* __restrict__ bv, float* __restrict__ dst) {
  int i = blockIdx.x * 256 + threadIdx.x;
  if (i < 2304) dst[i] = (i < 2048) ? bq[i] : (i < 2176 ? bk[i - 2048] : bv[i - 2176]);
}

// ---------------- bf16 GEMM: C[M][N] = A[M][K] * Bt[N][K]^T + bias[col] ----------------
// 128x128 tile, 4 waves (2x2 of 64x64), BK=32, mfma 16x16x32.
template<int OUT_BF16>
__global__ __launch_bounds__(256)
void k_gemm_bt(const unsigned short* __restrict__ A, const unsigned short* __restrict__ Bt,
               const float* __restrict__ bias, void* __restrict__ Cout,
               int M, int N, int K) {
  __shared__ unsigned short As[128][40];   // +8 pad: 2-way bank alias (free)
  __shared__ unsigned short Bs[128][40];
  const int tid  = threadIdx.x;
  const int lane = tid & 63, wid = tid >> 6;
  const int lr = lane & 15, lk = lane >> 4;
  const int wr = wid >> 1,  wc = wid & 1;
  const int mb = blockIdx.y * 128, nb = blockIdx.x * 128;
  const int srow = tid >> 2, scol = (tid & 3) * 8;
  const size_t Abase = (size_t)(mb + srow) * K + scol;
  const size_t Bbase = (size_t)(nb + srow) * K + scol;

  f32x4 acc[4][4];
  #pragma unroll
  for (int i = 0; i < 4; ++i)
    #pragma unroll
    for (int j = 0; j < 4; ++j) acc[i][j] = (f32x4){0.f, 0.f, 0.f, 0.f};

  const int kt_num = K >> 5;
  s16x8 av0 = *(const s16x8*)(A  + Abase);
  s16x8 av1 = *(const s16x8*)(A  + Abase + 64 * (size_t)K);
  s16x8 bv0 = *(const s16x8*)(Bt + Bbase);
  s16x8 bv1 = *(const s16x8*)(Bt + Bbase + 64 * (size_t)K);

  for (int kt = 0; kt < kt_num; ++kt) {
    __syncthreads();
    *(s16x8*)&As[srow][scol]      = av0;
    *(s16x8*)&As[srow + 64][scol] = av1;
    *(s16x8*)&Bs[srow][scol]      = bv0;
    *(s16x8*)&Bs[srow + 64][scol] = bv1;
    __syncthreads();
    if (kt + 1 < kt_num) {
      size_t off = (size_t)(kt + 1) * 32;
      av0 = *(const s16x8*)(A  + Abase + off);
      av1 = *(const s16x8*)(A  + Abase + 64 * (size_t)K + off);
      bv0 = *(const s16x8*)(Bt + Bbase + off);
      bv1 = *(const s16x8*)(Bt + Bbase + 64 * (size_t)K + off);
    }
    bf16x8 af[4], bfv[4];
    #pragma unroll
    for (int m = 0; m < 4; ++m) af[m]  = *(const bf16x8*)&As[wr * 64 + m * 16 + lr][lk * 8];
    #pragma unroll
    for (int n = 0; n < 4; ++n) bfv[n] = *(const bf16x8*)&Bs[wc * 64 + n * 16 + lr][lk * 8];
    #pragma unroll
    for (int m = 0; m < 4; ++m)
      #pragma unroll
      for (int n = 0; n < 4; ++n)
        acc[m][n] = __builtin_amdgcn_mfma_f32_16x16x32_bf16(af[m], bfv[n], acc[m][n], 0, 0, 0);
  }

  const int r0 = mb + wr * 64, c0 = nb + wc * 64;
  #pragma unroll
  for (int m = 0; m < 4; ++m) {
    #pragma unroll
    for (int n = 0; n < 4; ++n) {
      int col = c0 + n * 16 + lr;
      float bb = bias[col];
      #pragma unroll
      for (int r = 0; r < 4; ++r) {
        int row = r0 + m * 16 + lk * 4 + r;
        float v = acc[m][n][r] + bb;
        if (OUT_BF16) ((unsigned short*)Cout)[(size_t)row * N + col] = f2b(v);
        else          ((float*)Cout)[(size_t)row * N + col] = v;
      }
    }
  }
}

// ---------------- RoPE (q heads + k) ----------------
// qkv: [B*S][2304] bf16 (cols: h*128+d for q, 2048+d for k, 2176+d for v)
__global__ void k_rope(const unsigned short* __restrict__ qkv,
                       unsigned short* __restrict__ qr,  // [B][H][S][128]
                       unsigned short* __restrict__ kr,  // [B][S][128]
                       int S, int H) {
  int R = blockIdx.x * 4 + (threadIdx.x >> 6);
  int lane = threadIdx.x & 63;
  int per_b = S * (H + 1);
  int b = R / per_b;
  int rem = R - b * per_b;
  int s = rem / (H + 1);
  int j = rem - s * (H + 1);
  const unsigned short* src = qkv + (size_t)(b * S + s) * 2304 + (j < H ? j * 128 : 2048);
  float x1 = b2f(src[lane]);
  float x2 = b2f(src[lane + 64]);
  // inv_freq = 10000^(-lane/64) = exp(-lane * ln(1e4)/64)
  float invf = expf(-(float)lane * (9.210340371976184f / 64.0f));
  float ang = (float)s * invf;
  float c = cosf(ang), sn = sinf(ang);
  float o1 = x1 * c - x2 * sn;
  float o2 = x1 * sn + x2 * c;
  unsigned short* dst;
  if (j < H) dst = qr + ((size_t)(b * H + j) * S + s) * 128;
  else       dst = kr + ((size_t)(b * S) + s) * 128;
  dst[lane]      = f2b(o1);
  dst[lane + 64] = f2b(o2);
}

// ---------------- V transpose: vt[b][d][s] = qkv[b][s][2176+d] ----------------
__global__ void k_vtrans(const unsigned short* __restrict__ qkv,
                         unsigned short* __restrict__ vt, int S) {
  __shared__ unsigned short tile[32][33];
  int b = blockIdx.z;
  int s0 = blockIdx.x * 32, d0 = blockIdx.y * 32;
  int tx = threadIdx.x & 31, ty = threadIdx.x >> 5;
  for (int yy = ty; yy < 32; yy += 8)
    tile[yy][tx] = qkv[(size_t)(b * S + s0 + yy) * 2304 + 2176 + d0 + tx];
  __syncthreads();
  for (int yy = ty; yy < 32; yy += 8)
    vt[((size_t)b * 128 + d0 + yy) * S + s0 + tx] = tile[tx][yy];
}

// ---------------- causal flash attention (MQA: shared K/V) ----------------
// block: 64 q rows (4 waves x 16), iterate 32 keys; out[b][s][h*128+d] bf16
__global__ __launch_bounds__(256)
void k_attn(const unsigned short* __restrict__ qr,  // [B][H][S][128]
            const unsigned short* __restrict__ kr,  // [B][S][128]
            const unsigned short* __restrict__ vt,  // [B][128][S]
            unsigned short* __restrict__ attn_out,  // [B][S][2048]
            int S, int H) {
  const int b = blockIdx.z, h = blockIdx.y;
  const int qb0 = blockIdx.x * 64;
  const int tid = threadIdx.x, wid = tid >> 6, lane = tid & 63;
  const int lr = lane & 15, lk = lane >> 4;
  const int qw = qb0 + wid * 16;
  __shared__ unsigned short P_all[4][16][40];
  unsigned short (*P_lds)[40] = P_all[wid];

  const unsigned short* qptr = qr + ((size_t)(b * H + h) * S + (qw + lr)) * 128;
  bf16x8 aq[4];
  #pragma unroll
  for (int kk = 0; kk < 4; ++kk) aq[kk] = *(const bf16x8*)(qptr + kk * 32 + lk * 8);

  float mrun[4], lrun[4];
  f32x4 accO[8];
  #pragma unroll
  for (int r = 0; r < 4; ++r) { mrun[r] = -1e30f; lrun[r] = 0.f; }
  #pragma unroll
  for (int t = 0; t < 8; ++t) accO[t] = (f32x4){0.f, 0.f, 0.f, 0.f};

  const float scale = 0.08838834764831845f;  // 1/sqrt(128)
  const int kv_end = qb0 + 64;
  for (int kb = 0; kb < kv_end; kb += 32) {
    if (kb > qw + 15) break;  // wave-uniform causal early-out
    f32x4 sc[2];
    #pragma unroll
    for (int j = 0; j < 2; ++j) {
      f32x4 s4 = (f32x4){0.f, 0.f, 0.f, 0.f};
      const unsigned short* kp = kr + ((size_t)b * S + (kb + j * 16 + lr)) * 128;
      #pragma unroll
      for (int kk = 0; kk < 4; ++kk) {
        bf16x8 bk = *(const bf16x8*)(kp + kk * 32 + lk * 8);
        s4 = __builtin_amdgcn_mfma_f32_16x16x32_bf16(aq[kk], bk, s4, 0, 0, 0);
      }
      sc[j] = s4;
    }
    float sf[4];
    #pragma unroll
    for (int r = 0; r < 4; ++r) {
      int qrow = qw + lk * 4 + r;
      float t0 = sc[0][r] * scale; if (kb + lr > qrow)      t0 = -1e30f;
      float t1 = sc[1][r] * scale; if (kb + 16 + lr > qrow) t1 = -1e30f;
      float mx = fmaxf(t0, t1);
      mx = fmaxf(mx, __shfl_xor(mx, 1));
      mx = fmaxf(mx, __shfl_xor(mx, 2));
      mx = fmaxf(mx, __shfl_xor(mx, 4));
      mx = fmaxf(mx, __shfl_xor(mx, 8));
      float mnew = fmaxf(mrun[r], mx);
      sf[r] = __expf(mrun[r] - mnew);
      mrun[r] = mnew;
      float p0 = __expf(t0 - mnew);
      float p1 = __expf(t1 - mnew);
      float sum = p0 + p1;
      sum += __shfl_xor(sum, 1);
      sum += __shfl_xor(sum, 2);
      sum += __shfl_xor(sum, 4);
      sum += __shfl_xor(sum, 8);
      lrun[r] = lrun[r] * sf[r] + sum;
      P_lds[lk * 4 + r][lr]      = f2b(p0);
      P_lds[lk * 4 + r][16 + lr] = f2b(p1);
    }
    #pragma unroll
    for (int t = 0; t < 8; ++t)
      #pragma unroll
      for (int r = 0; r < 4; ++r) accO[t][r] *= sf[r];
    bf16x8 pa = *(const bf16x8*)&P_lds[lr][lk * 8];
    #pragma unroll
    for (int t = 0; t < 8; ++t) {
      const unsigned short* vp = vt + ((size_t)b * 128 + t * 16 + lr) * S + kb + lk * 8;
      bf16x8 bv = *(const bf16x8*)vp;
      accO[t] = __builtin_amdgcn_mfma_f32_16x16x32_bf16(pa, bv, accO[t], 0, 0, 0);
    }
  }
  #pragma unroll
  for (int t = 0; t < 8; ++t) {
    #pragma unroll
    for (int r = 0; r < 4; ++r) {
      int srow = qw + lk * 4 + r;
      float o = accO[t][r] / lrun[r];
      attn_out[((size_t)(b * S) + srow) * 2048 + h * 128 + t * 16 + lr] = f2b(o);
    }
  }
}

// ---------------- launch ----------------
extern "C" void kernel_launch(void* const* d_in, const int* in_sizes, int n_in,
                              void* d_out, int out_size, void* d_ws, size_t ws_size,
                              hipStream_t stream) {
  const float* x  = (const float*)d_in[0];
  const float* Wq = (const float*)d_in[1];
  const float* bq = (const float*)d_in[2];
  const float* Wk = (const float*)d_in[3];
  const float* bk = (const float*)d_in[4];
  const float* Wv = (const float*)d_in[5];
  const float* bv = (const float*)d_in[6];
  const float* Wo = (const float*)d_in[7];
  const float* bo = (const float*)d_in[8];
  float* out = (float*)d_out;

  const int B = 2, S = 2048, E = 2048, H = 16, D = 128;
  const int M = B * S;             // 4096
  const int Nqkv = H * D + 2 * D;  // 2304

  char* w = (char*)d_ws;
  unsigned short* xb    = (unsigned short*)w;                              // 16,777,216 B
  unsigned short* WqkvT = (unsigned short*)(w + 16777216);                 //  9,437,184 B
  unsigned short* qkv   = (unsigned short*)(w + 16777216 + 9437184);       // 18,874,368 B
  unsigned short* qr    = (unsigned short*)(w + 16777216 + 9437184 + 18874368); // 16,777,216 B
  unsigned short* kr    = qr + (size_t)B * H * S * D;
  unsigned short* vtb   = kr + (size_t)B * S * D;
  float*          cbias = (float*)(vtb + (size_t)B * S * D);
  unsigned short* attn_out = xb;     // alias: xb dead after gemm1
  unsigned short* WoT      = WqkvT;  // alias: WqkvT dead after gemm1

  k_cvt_bf16<<<dim3((M * E / 4) / 256), 256, 0, stream>>>(x, xb, M * E / 4);
  k_transpose<<<dim3(Nqkv / 32, E / 32), 256, 0, stream>>>(Wq, H * D, Wk, D, Wv, WqkvT, E);
  k_bias_concat<<<dim3(9), 256, 0, stream>>>(bq, bk, bv, cbias);
  k_gemm_bt<1><<<dim3(Nqkv / 128, M / 128), 256, 0, stream>>>(xb, WqkvT, cbias, (void*)qkv, M, Nqkv, E);
  k_rope<<<dim3(B * S * (H + 1) / 4), 256, 0, stream>>>(qkv, qr, kr, S, H);
  k_vtrans<<<dim3(S / 32, D / 32, B), 256, 0, stream>>>(qkv, vtb, S);
  k_transpose<<<dim3(E / 32, (H * D) / 32), 256, 0, stream>>>(Wo, E, nullptr, 0, nullptr, WoT, H * D);
  k_attn<<<dim3(S / 64, H, B), 256, 0, stream>>>(qr, kr, vtb, attn_out, S, H);
  k_gemm_bt<0><<<dim3(E / 128, M / 128), 256, 0, stream>>>(attn_out, WoT, bo, (void*)d_out, M, E, H * D);
}

// Round 2
// 434.365 us; speedup vs baseline: 1.3817x; 1.3817x over previous
//
#include <hip/hip_runtime.h>
#include <stdint.h>

typedef __bf16 bf16x8 __attribute__((ext_vector_type(8)));
typedef float  f32x4  __attribute__((ext_vector_type(4)));
typedef short  s16x8  __attribute__((ext_vector_type(8)));

__device__ inline unsigned short f2b(float f) {
  unsigned int u = __builtin_bit_cast(unsigned int, f);
  u += 0x7FFFu + ((u >> 16) & 1u);
  return (unsigned short)(u >> 16);
}
__device__ inline float b2f(unsigned short h) {
  unsigned int u = ((unsigned int)h) << 16;
  return __builtin_bit_cast(float, u);
}
__device__ inline unsigned int pk2(float a, float b) {
  return (unsigned int)f2b(a) | ((unsigned int)f2b(b) << 16);
}

// ---------------- elementwise f32 -> bf16 ----------------
__global__ void k_cvt_bf16(const float* __restrict__ in, unsigned short* __restrict__ out, int n4) {
  int i = blockIdx.x * blockDim.x + threadIdx.x;
  if (i < n4) {
    float4 v = ((const float4*)in)[i];
    ushort4 o;
    o.x = f2b(v.x); o.y = f2b(v.y); o.z = f2b(v.z); o.w = f2b(v.w);
    ((ushort4*)out)[i] = o;
  }
}

// ---------------- transpose f32 [K][N]-segments -> bf16 [N][K] ----------------
__global__ void k_transpose(const float* __restrict__ A, int nA,
                            const float* __restrict__ Bsrc, int nB,
                            const float* __restrict__ Csrc,
                            unsigned short* __restrict__ dst, int K) {
  __shared__ float tile[32][33];
  int n0 = blockIdx.x * 32;
  int k0 = blockIdx.y * 32;
  const float* src; int ldn, noff;
  if (n0 < nA)            { src = A;    ldn = nA; noff = n0; }
  else if (n0 < nA + nB)  { src = Bsrc; ldn = nB; noff = n0 - nA; }
  else                    { src = Csrc; ldn = nB; noff = n0 - nA - nB; }
  int tx = threadIdx.x & 31, ty = threadIdx.x >> 5;
  for (int yy = ty; yy < 32; yy += 8)
    tile[yy][tx] = src[(size_t)(k0 + yy) * ldn + noff + tx];
  __syncthreads();
  for (int yy = ty; yy < 32; yy += 8)
    dst[(size_t)(n0 + yy) * K + k0 + tx] = f2b(tile[tx][yy]);
}

// ---------------- bias concat [2304] ----------------
__global__ void k_bias_concat(const float* __restrict__ bq, const float* __restrict__ bk,
                              const float* __restrict__ bv, float* __restrict__ dst) {
  int i = blockIdx.x * 256 + threadIdx.x;
  if (i < 2304) dst[i] = (i < 2048) ? bq[i] : (i < 2176 ? bk[i - 2048] : bv[i - 2176]);
}

// ---------------- bf16 GEMM: C[M][N] = A[M][K] * Bt[N][K]^T + bias[col] ----------------
template<int OUT_BF16>
__global__ __launch_bounds__(256)
void k_gemm_bt(const unsigned short* __restrict__ A, const unsigned short* __restrict__ Bt,
               const float* __restrict__ bias, void* __restrict__ Cout,
               int M, int N, int K) {
  __shared__ unsigned short As[128][40];
  __shared__ unsigned short Bs[128][40];
  const int tid  = threadIdx.x;
  const int lane = tid & 63, wid = tid >> 6;
  const int lr = lane & 15, lk = lane >> 4;
  const int wr = wid >> 1,  wc = wid & 1;
  const int mb = blockIdx.y * 128, nb = blockIdx.x * 128;
  const int srow = tid >> 2, scol = (tid & 3) * 8;
  const size_t Abase = (size_t)(mb + srow) * K + scol;
  const size_t Bbase = (size_t)(nb + srow) * K + scol;

  f32x4 acc[4][4];
  #pragma unroll
  for (int i = 0; i < 4; ++i)
    #pragma unroll
    for (int j = 0; j < 4; ++j) acc[i][j] = (f32x4){0.f, 0.f, 0.f, 0.f};

  const int kt_num = K >> 5;
  s16x8 av0 = *(const s16x8*)(A  + Abase);
  s16x8 av1 = *(const s16x8*)(A  + Abase + 64 * (size_t)K);
  s16x8 bv0 = *(const s16x8*)(Bt + Bbase);
  s16x8 bv1 = *(const s16x8*)(Bt + Bbase + 64 * (size_t)K);

  for (int kt = 0; kt < kt_num; ++kt) {
    __syncthreads();
    *(s16x8*)&As[srow][scol]      = av0;
    *(s16x8*)&As[srow + 64][scol] = av1;
    *(s16x8*)&Bs[srow][scol]      = bv0;
    *(s16x8*)&Bs[srow + 64][scol] = bv1;
    __syncthreads();
    if (kt + 1 < kt_num) {
      size_t off = (size_t)(kt + 1) * 32;
      av0 = *(const s16x8*)(A  + Abase + off);
      av1 = *(const s16x8*)(A  + Abase + 64 * (size_t)K + off);
      bv0 = *(const s16x8*)(Bt + Bbase + off);
      bv1 = *(const s16x8*)(Bt + Bbase + 64 * (size_t)K + off);
    }
    bf16x8 af[4], bfv[4];
    #pragma unroll
    for (int m = 0; m < 4; ++m) af[m]  = *(const bf16x8*)&As[wr * 64 + m * 16 + lr][lk * 8];
    #pragma unroll
    for (int n = 0; n < 4; ++n) bfv[n] = *(const bf16x8*)&Bs[wc * 64 + n * 16 + lr][lk * 8];
    #pragma unroll
    for (int m = 0; m < 4; ++m)
      #pragma unroll
      for (int n = 0; n < 4; ++n)
        acc[m][n] = __builtin_amdgcn_mfma_f32_16x16x32_bf16(af[m], bfv[n], acc[m][n], 0, 0, 0);
  }

  const int r0 = mb + wr * 64, c0 = nb + wc * 64;
  #pragma unroll
  for (int m = 0; m < 4; ++m) {
    #pragma unroll
    for (int n = 0; n < 4; ++n) {
      int col = c0 + n * 16 + lr;
      float bb = bias[col];
      #pragma unroll
      for (int r = 0; r < 4; ++r) {
        int row = r0 + m * 16 + lk * 4 + r;
        float v = acc[m][n][r] + bb;
        if (OUT_BF16) ((unsigned short*)Cout)[(size_t)row * N + col] = f2b(v);
        else          ((float*)Cout)[(size_t)row * N + col] = v;
      }
    }
  }
}

// ---------------- RoPE (q heads + k) ----------------
__global__ void k_rope(const unsigned short* __restrict__ qkv,
                       unsigned short* __restrict__ qr,
                       unsigned short* __restrict__ kr,
                       int S, int H) {
  int R = blockIdx.x * 4 + (threadIdx.x >> 6);
  int lane = threadIdx.x & 63;
  int per_b = S * (H + 1);
  int b = R / per_b;
  int rem = R - b * per_b;
  int s = rem / (H + 1);
  int j = rem - s * (H + 1);
  const unsigned short* src = qkv + (size_t)(b * S + s) * 2304 + (j < H ? j * 128 : 2048);
  float x1 = b2f(src[lane]);
  float x2 = b2f(src[lane + 64]);
  float invf = expf(-(float)lane * (9.210340371976184f / 64.0f));
  float ang = (float)s * invf;
  float c = cosf(ang), sn = sinf(ang);
  float o1 = x1 * c - x2 * sn;
  float o2 = x1 * sn + x2 * c;
  unsigned short* dst;
  if (j < H) dst = qr + ((size_t)(b * H + j) * S + s) * 128;
  else       dst = kr + ((size_t)(b * S) + s) * 128;
  dst[lane]      = f2b(o1);
  dst[lane + 64] = f2b(o2);
}

// ---------------- V transpose ----------------
__global__ void k_vtrans(const unsigned short* __restrict__ qkv,
                         unsigned short* __restrict__ vt, int S) {
  __shared__ unsigned short tile[32][33];
  int b = blockIdx.z;
  int s0 = blockIdx.x * 32, d0 = blockIdx.y * 32;
  int tx = threadIdx.x & 31, ty = threadIdx.x >> 5;
  for (int yy = ty; yy < 32; yy += 8)
    tile[yy][tx] = qkv[(size_t)(b * S + s0 + yy) * 2304 + 2176 + d0 + tx];
  __syncthreads();
  for (int yy = ty; yy < 32; yy += 8)
    vt[((size_t)b * 128 + d0 + yy) * S + s0 + tx] = tile[tx][yy];
}

// ---------------- causal flash attention (MQA, swapped QK^T) ----------------
// Block: 64 q rows (4 waves x 16). KV tile = 64 keys. Each block handles two
// q-tiles (i and 31-i) for uniform causal work. Swapped mfma(K,Q): lane holds
// one q-row's scores -> in-lane softmax reduce (2 shuffles/tile).
__global__ __launch_bounds__(256)
void k_attn(const unsigned short* __restrict__ qr,  // [B][H][S][128]
            const unsigned short* __restrict__ kr,  // [B][S][128]
            const unsigned short* __restrict__ vt,  // [B][128][S]
            unsigned short* __restrict__ attn_out,  // [B][S][2048]
            int S, int H) {
  const int b = blockIdx.z, h = blockIdx.y;
  const int tid = threadIdx.x, wid = tid >> 6, lane = tid & 63;
  const int lr = lane & 15, lk = lane >> 4;
  __shared__ unsigned short P_all[4][16][72];
  unsigned short (*P)[72] = P_all[wid];

  const int ntiles = gridDim.x * 2;
  const float scale = 0.08838834764831845f;  // 1/sqrt(128)

  #pragma unroll 1
  for (int half = 0; half < 2; ++half) {
    const int qt  = (half == 0) ? blockIdx.x : (ntiles - 1 - blockIdx.x);
    const int qb0 = qt * 64;
    const int qw  = qb0 + wid * 16;

    const unsigned short* qptr = qr + ((size_t)(b * H + h) * S + (qw + lr)) * 128;
    bf16x8 aq[4];
    #pragma unroll
    for (int kk = 0; kk < 4; ++kk) aq[kk] = *(const bf16x8*)(qptr + kk * 32 + lk * 8);

    float mrun = -1e30f, lrun = 0.f;
    f32x4 accO[8];
    #pragma unroll
    for (int t = 0; t < 8; ++t) accO[t] = (f32x4){0.f, 0.f, 0.f, 0.f};

    #pragma unroll 1
    for (int kb = 0; kb <= qb0; kb += 64) {
      const bool diag = (kb == qb0);
      // ---- QK^T (swapped): s4[m][r] = S[key = kb+m*16+lk*4+r][q = qw+lr]
      f32x4 s4[4];
      #pragma unroll
      for (int m = 0; m < 4; ++m) {
        f32x4 acc = (f32x4){0.f, 0.f, 0.f, 0.f};
        const unsigned short* kp = kr + ((size_t)b * S + (kb + m * 16 + lr)) * 128;
        #pragma unroll
        for (int kk = 0; kk < 4; ++kk) {
          bf16x8 kf = *(const bf16x8*)(kp + kk * 32 + lk * 8);
          acc = __builtin_amdgcn_mfma_f32_16x16x32_bf16(kf, aq[kk], acc, 0, 0, 0);
        }
        s4[m] = acc;
      }
      // ---- scale + (diagonal-only) mask, in-lane max
      float mx = -1e30f;
      #pragma unroll
      for (int m = 0; m < 4; ++m) {
        #pragma unroll
        for (int r = 0; r < 4; ++r) {
          float v = s4[m][r] * scale;
          if (diag && (kb + m * 16 + lk * 4 + r) > (qw + lr)) v = -1e30f;
          s4[m][r] = v;
          mx = fmaxf(mx, v);
        }
      }
      mx = fmaxf(mx, __shfl_xor(mx, 16));
      mx = fmaxf(mx, __shfl_xor(mx, 32));
      const float mnew = fmaxf(mrun, mx);
      const float sf   = __expf(mrun - mnew);
      mrun = mnew;
      // ---- exp, sum, pack P -> LDS
      float sum = 0.f;
      #pragma unroll
      for (int m = 0; m < 4; ++m) {
        float p0 = __expf(s4[m][0] - mnew);
        float p1 = __expf(s4[m][1] - mnew);
        float p2 = __expf(s4[m][2] - mnew);
        float p3 = __expf(s4[m][3] - mnew);
        sum += (p0 + p1) + (p2 + p3);
        uint2 w;
        w.x = pk2(p0, p1);
        w.y = pk2(p2, p3);
        *(uint2*)&P[lr][m * 16 + lk * 4] = w;
      }
      sum += __shfl_xor(sum, 16);
      sum += __shfl_xor(sum, 32);
      lrun = lrun * sf + sum;
      // ---- rescale O (per-output-row factors via bpermute)
      float sfr[4];
      #pragma unroll
      for (int r = 0; r < 4; ++r) sfr[r] = __shfl(sf, lk * 4 + r);
      #pragma unroll
      for (int t = 0; t < 8; ++t)
        #pragma unroll
        for (int r = 0; r < 4; ++r) accO[t][r] *= sfr[r];
      // ---- PV
      #pragma unroll
      for (int ks = 0; ks < 2; ++ks) {
        bf16x8 pa = *(const bf16x8*)&P[lr][ks * 32 + lk * 8];
        #pragma unroll
        for (int t = 0; t < 8; ++t) {
          const unsigned short* vp = vt + ((size_t)b * 128 + t * 16 + lr) * S + kb + ks * 32 + lk * 8;
          bf16x8 bv = *(const bf16x8*)vp;
          accO[t] = __builtin_amdgcn_mfma_f32_16x16x32_bf16(pa, bv, accO[t], 0, 0, 0);
        }
      }
    }
    // ---- epilogue: divide by l, store
    float lr4[4];
    #pragma unroll
    for (int r = 0; r < 4; ++r) lr4[r] = __shfl(lrun, lk * 4 + r);
    #pragma unroll
    for (int t = 0; t < 8; ++t) {
      #pragma unroll
      for (int r = 0; r < 4; ++r) {
        int srow = qw + lk * 4 + r;
        float o = accO[t][r] / lr4[r];
        attn_out[((size_t)(b * S) + srow) * 2048 + h * 128 + t * 16 + lr] = f2b(o);
      }
    }
  }
}

// ---------------- launch ----------------
extern "C" void kernel_launch(void* const* d_in, const int* in_sizes, int n_in,
                              void* d_out, int out_size, void* d_ws, size_t ws_size,
                              hipStream_t stream) {
  const float* x  = (const float*)d_in[0];
  const float* Wq = (const float*)d_in[1];
  const float* bq = (const float*)d_in[2];
  const float* Wk = (const float*)d_in[3];
  const float* bk = (const float*)d_in[4];
  const float* Wv = (const float*)d_in[5];
  const float* bv = (const float*)d_in[6];
  const float* Wo = (const float*)d_in[7];
  const float* bo = (const float*)d_in[8];

  const int B = 2, S = 2048, E = 2048, H = 16, D = 128;
  const int M = B * S;             // 4096
  const int Nqkv = H * D + 2 * D;  // 2304

  char* w = (char*)d_ws;
  unsigned short* xb    = (unsigned short*)w;                              // 16,777,216 B
  unsigned short* WqkvT = (unsigned short*)(w + 16777216);                 //  9,437,184 B
  unsigned short* qkv   = (unsigned short*)(w + 16777216 + 9437184);       // 18,874,368 B
  unsigned short* qr    = (unsigned short*)(w + 16777216 + 9437184 + 18874368); // 16,777,216 B
  unsigned short* kr    = qr + (size_t)B * H * S * D;
  unsigned short* vtb   = kr + (size_t)B * S * D;
  float*          cbias = (float*)(vtb + (size_t)B * S * D);
  unsigned short* attn_out = xb;     // alias: xb dead after gemm1
  unsigned short* WoT      = WqkvT;  // alias: WqkvT dead after gemm1

  k_cvt_bf16<<<dim3((M * E / 4) / 256), 256, 0, stream>>>(x, xb, M * E / 4);
  k_transpose<<<dim3(Nqkv / 32, E / 32), 256, 0, stream>>>(Wq, H * D, Wk, D, Wv, WqkvT, E);
  k_bias_concat<<<dim3(9), 256, 0, stream>>>(bq, bk, bv, cbias);
  k_gemm_bt<1><<<dim3(Nqkv / 128, M / 128), 256, 0, stream>>>(xb, WqkvT, cbias, (void*)qkv, M, Nqkv, E);
  k_rope<<<dim3(B * S * (H + 1) / 4), 256, 0, stream>>>(qkv, qr, kr, S, H);
  k_vtrans<<<dim3(S / 32, D / 32, B), 256, 0, stream>>>(qkv, vtb, S);
  k_transpose<<<dim3(E / 32, (H * D) / 32), 256, 0, stream>>>(Wo, E, nullptr, 0, nullptr, WoT, H * D);
  k_attn<<<dim3(S / 128, H, B), 256, 0, stream>>>(qr, kr, vtb, attn_out, S, H);
  k_gemm_bt<0><<<dim3(E / 128, M / 128), 256, 0, stream>>>(attn_out, WoT, bo, (void*)d_out, M, E, H * D);
}